// Round 1
// baseline (361.586 us; speedup 1.0000x reference)
//
#include <hip/hip_runtime.h>
#include <hip/hip_bf16.h>
#include <cstdint>

// ---------------------------------------------------------------------------
// SelfAttention: q,k,v = x@W{q,k,v}^T + b ; P = softmax(qk^T/sqrt(H)) ; out = P@v
// B=4, S=2048, H=I=1024. fp32 I/O, bf16 MFMA internally (tol 6.25e-3).
// ---------------------------------------------------------------------------

typedef __bf16 bf16x8 __attribute__((ext_vector_type(8)));
typedef float  f32x4  __attribute__((ext_vector_type(4)));

__device__ __forceinline__ void load_lds16(const __bf16* g, __bf16* l) {
    __builtin_amdgcn_global_load_lds(
        (const __attribute__((address_space(1))) void*)g,
        (__attribute__((address_space(3))) void*)l,
        16, 0, 0);
}

// ---------------- fp32 -> bf16 convert (8 elems / thread) ------------------
__global__ __launch_bounds__(256) void cvt_f32_bf16(
        const float* __restrict__ src, __bf16* __restrict__ dst, int n8) {
    int i = blockIdx.x * blockDim.x + threadIdx.x;
    if (i >= n8) return;
    const float4* s4 = (const float4*)src;
    float4 a = s4[2 * i], b = s4[2 * i + 1];
    bf16x8 o;
    o[0] = (__bf16)a.x; o[1] = (__bf16)a.y; o[2] = (__bf16)a.z; o[3] = (__bf16)a.w;
    o[4] = (__bf16)b.x; o[5] = (__bf16)b.y; o[6] = (__bf16)b.z; o[7] = (__bf16)b.w;
    ((bf16x8*)dst)[i] = o;
}

// ---------------- NT bf16 GEMM: C[m,n] = sum_k A[m,k] * Bt[n,k] ------------
// 128x128 tile, BK=32, 4 waves (2x2 of 64x64), 16x16x32 MFMA, 4x4 frags/wave.
// MODE 0: C_bf16 = acc + bias[n]   (QKV projection)
// MODE 1: C_f32  = acc * scale     (scores)
// MODE 2: C_f32  = acc             (PV)
template <int MODE>
__global__ __launch_bounds__(256, 2) void gemm_nt(
        const __bf16* __restrict__ A, const __bf16* __restrict__ Bt,
        void* __restrict__ Cout, const float* __restrict__ bias,
        int M, int N, int K, long sA, long sB, long sC, float scale) {
    __shared__ __bf16 lA[128 * 32];
    __shared__ __bf16 lB[128 * 32];

    const int tid  = threadIdx.x;
    const int lane = tid & 63;
    const int wave = tid >> 6;
    const int mblk = blockIdx.y * 128;
    const int nblk = blockIdx.x * 128;
    const int z    = blockIdx.z;
    A  += (long)z * sA;
    Bt += (long)z * sB;

    const int wm = (wave >> 1) * 64;   // wave m offset in tile
    const int wn = (wave & 1) * 64;    // wave n offset in tile

    f32x4 zero = {0.f, 0.f, 0.f, 0.f};
    f32x4 acc[4][4];
#pragma unroll
    for (int i = 0; i < 4; ++i)
#pragma unroll
        for (int j = 0; j < 4; ++j) acc[i][j] = zero;

    const int kq   = (lane >> 4) * 8;  // k offset of this lane's fragment
    const int rsel = lane & 15;        // row-in-16 selector for A/B frags

    for (int k0 = 0; k0 < K; k0 += 32) {
        // stage A and B tiles: 512 chunks of 16B each, 2 per thread
#pragma unroll
        for (int it = 0; it < 2; ++it) {
            int c   = tid + it * 256;
            int row = c >> 2;
            int col = (c & 3) * 8;
            load_lds16(A  + (long)(mblk + row) * K + k0 + col, lA + c * 8);
            load_lds16(Bt + (long)(nblk + row) * K + k0 + col, lB + c * 8);
        }
        __syncthreads();

        bf16x8 fa[4], fb[4];
#pragma unroll
        for (int i = 0; i < 4; ++i) {
            fa[i] = *(const bf16x8*)&lA[(wm + i * 16 + rsel) * 32 + kq];
            fb[i] = *(const bf16x8*)&lB[(wn + i * 16 + rsel) * 32 + kq];
        }
#pragma unroll
        for (int i = 0; i < 4; ++i)
#pragma unroll
            for (int j = 0; j < 4; ++j)
                acc[i][j] = __builtin_amdgcn_mfma_f32_16x16x32_bf16(
                    fa[i], fb[j], acc[i][j], 0, 0, 0);
        __syncthreads();
    }

    // epilogue: lane holds C[m = wm+i*16+(lane>>4)*4+r][n = wn+j*16+(lane&15)]
    const int rq = (lane >> 4) * 4;
#pragma unroll
    for (int i = 0; i < 4; ++i) {
#pragma unroll
        for (int j = 0; j < 4; ++j) {
            const int n = nblk + wn + j * 16 + rsel;
            if constexpr (MODE == 0) {
                __bf16* C = (__bf16*)Cout + (long)z * sC;
                float bv = bias[n];
#pragma unroll
                for (int r = 0; r < 4; ++r) {
                    int m = mblk + wm + i * 16 + rq + r;
                    C[(long)m * N + n] = (__bf16)(acc[i][j][r] + bv);
                }
            } else if constexpr (MODE == 1) {
                float* C = (float*)Cout + (long)z * sC;
#pragma unroll
                for (int r = 0; r < 4; ++r) {
                    int m = mblk + wm + i * 16 + rq + r;
                    C[(long)m * N + n] = acc[i][j][r] * scale;
                }
            } else {
                float* C = (float*)Cout + (long)z * sC;
#pragma unroll
                for (int r = 0; r < 4; ++r) {
                    int m = mblk + wm + i * 16 + rq + r;
                    C[(long)m * N + n] = acc[i][j][r];
                }
            }
        }
    }
}

// ---------------- row softmax over 2048 floats, in-place + bf16 copy -------
__global__ __launch_bounds__(256) void softmax_rows(
        float* __restrict__ P, __bf16* __restrict__ Pb) {
    const long row = blockIdx.x;           // 8192 rows
    float*  p  = P  + row * 2048;
    __bf16* pb = Pb + row * 2048;
    const int tid  = threadIdx.x;
    const int lane = tid & 63;
    const int wave = tid >> 6;

    float4 v0 = ((const float4*)p)[tid * 2];
    float4 v1 = ((const float4*)p)[tid * 2 + 1];
    float e[8] = {v0.x, v0.y, v0.z, v0.w, v1.x, v1.y, v1.z, v1.w};

    float mx = e[0];
#pragma unroll
    for (int i = 1; i < 8; ++i) mx = fmaxf(mx, e[i]);
#pragma unroll
    for (int o = 1; o < 64; o <<= 1) mx = fmaxf(mx, __shfl_xor(mx, o, 64));

    __shared__ float redm[4], reds[4];
    if (lane == 0) redm[wave] = mx;
    __syncthreads();
    mx = fmaxf(fmaxf(redm[0], redm[1]), fmaxf(redm[2], redm[3]));

    float sum = 0.f;
#pragma unroll
    for (int i = 0; i < 8; ++i) { e[i] = __expf(e[i] - mx); sum += e[i]; }
#pragma unroll
    for (int o = 1; o < 64; o <<= 1) sum += __shfl_xor(sum, o, 64);
    if (lane == 0) reds[wave] = sum;
    __syncthreads();
    sum = reds[0] + reds[1] + reds[2] + reds[3];
    const float inv = 1.f / sum;

    float4 o0, o1;
    o0.x = e[0] * inv; o0.y = e[1] * inv; o0.z = e[2] * inv; o0.w = e[3] * inv;
    o1.x = e[4] * inv; o1.y = e[5] * inv; o1.z = e[6] * inv; o1.w = e[7] * inv;
    ((float4*)p)[tid * 2]     = o0;
    ((float4*)p)[tid * 2 + 1] = o1;
    bf16x8 ob;
    ob[0] = (__bf16)o0.x; ob[1] = (__bf16)o0.y; ob[2] = (__bf16)o0.z; ob[3] = (__bf16)o0.w;
    ob[4] = (__bf16)o1.x; ob[5] = (__bf16)o1.y; ob[6] = (__bf16)o1.z; ob[7] = (__bf16)o1.w;
    ((bf16x8*)pb)[tid] = ob;
}

// ---------------- bf16 transpose: V[b][t][h] -> Vt[b][h][t] ----------------
__global__ __launch_bounds__(256) void transpose_v(
        const __bf16* __restrict__ src, __bf16* __restrict__ dst) {
    __shared__ __bf16 t[32][33];
    const int tx = threadIdx.x, ty = threadIdx.y;   // (32, 8)
    const int tileC = blockIdx.x * 32;              // h base (0..1023)
    const int tileR = blockIdx.y * 32;              // t base (0..2047)
    const long zs = (long)blockIdx.z * 2048 * 1024;
    const long zd = (long)blockIdx.z * 1024 * 2048;
#pragma unroll
    for (int k = 0; k < 4; ++k) {
        int r = ty * 4 + k;
        t[r][tx] = src[zs + (long)(tileR + r) * 1024 + tileC + tx];
    }
    __syncthreads();
#pragma unroll
    for (int k = 0; k < 4; ++k) {
        int c = ty * 4 + k;
        dst[zd + (long)(tileC + c) * 2048 + tileR + tx] = t[tx][c];
    }
}

// ---------------------------------------------------------------------------
extern "C" void kernel_launch(void* const* d_in, const int* in_sizes, int n_in,
                              void* d_out, int out_size, void* d_ws, size_t ws_size,
                              hipStream_t stream) {
    const float* x  = (const float*)d_in[0];
    const float* Wq = (const float*)d_in[1];
    const float* bq = (const float*)d_in[2];
    const float* Wk = (const float*)d_in[3];
    const float* bk = (const float*)d_in[4];
    const float* Wv = (const float*)d_in[5];
    const float* bv = (const float*)d_in[6];

    const int  S = 2048, H = 1024, I = 1024, B = 4;
    const long MS = (long)B * S;              // 8192 rows
    float* out_ws  = (float*)d_out;                     // [B][S][H]
    float* out_att = (float*)d_out + (long)B * S * H;   // [B][S][S]

    char* w = (char*)d_ws;
    __bf16* x_bf  = (__bf16*)w; w += MS * I * 2;         // 16 MB
    __bf16* wq_bf = (__bf16*)w; w += (long)H * I * 2;    //  2 MB
    __bf16* wk_bf = (__bf16*)w; w += (long)H * I * 2;
    __bf16* wv_bf = (__bf16*)w; w += (long)H * I * 2;
    __bf16* q_bf  = (__bf16*)w; w += MS * H * 2;         // 16 MB
    __bf16* k_bf  = (__bf16*)w; w += MS * H * 2;
    __bf16* v_bf  = (__bf16*)w; w += MS * H * 2;
    __bf16* vt_bf = (__bf16*)w; w += MS * H * 2;
    __bf16* p_bf  = (__bf16*)w; w += (long)B * S * S * 2; // 32 MB  (total 118 MB)

    // 1) converts
    {
        int n8 = (int)(MS * I / 8);
        cvt_f32_bf16<<<dim3((n8 + 255) / 256), dim3(256), 0, stream>>>(x, x_bf, n8);
        int w8 = H * I / 8;
        cvt_f32_bf16<<<dim3((w8 + 255) / 256), dim3(256), 0, stream>>>(Wq, wq_bf, w8);
        cvt_f32_bf16<<<dim3((w8 + 255) / 256), dim3(256), 0, stream>>>(Wk, wk_bf, w8);
        cvt_f32_bf16<<<dim3((w8 + 255) / 256), dim3(256), 0, stream>>>(Wv, wv_bf, w8);
    }

    // 2) QKV projections: M=8192, N=1024, K=1024
    gemm_nt<0><<<dim3(8, 64, 1), dim3(256), 0, stream>>>(
        x_bf, wq_bf, q_bf, bq, 8192, 1024, 1024, 0, 0, 0, 1.f);
    gemm_nt<0><<<dim3(8, 64, 1), dim3(256), 0, stream>>>(
        x_bf, wk_bf, k_bf, bk, 8192, 1024, 1024, 0, 0, 0, 1.f);
    gemm_nt<0><<<dim3(8, 64, 1), dim3(256), 0, stream>>>(
        x_bf, wv_bf, v_bf, bv, 8192, 1024, 1024, 0, 0, 0, 1.f);

    // 3) V transpose for PV GEMM
    transpose_v<<<dim3(32, 64, 4), dim3(32, 8), 0, stream>>>(v_bf, vt_bf);

    // 4) scores = Q K^T * 1/32 -> fp32 straight into attn-weights output region
    gemm_nt<1><<<dim3(16, 16, 4), dim3(256), 0, stream>>>(
        q_bf, k_bf, out_att, nullptr, 2048, 2048, 1024,
        (long)S * H, (long)S * H, (long)S * S, 0.03125f);

    // 5) softmax rows in-place (+ bf16 copy for PV)
    softmax_rows<<<dim3(8192), dim3(256), 0, stream>>>(out_att, p_bf);

    // 6) weighted_sum = P V : M=2048, N=1024, K=2048
    gemm_nt<2><<<dim3(8, 16, 4), dim3(256), 0, stream>>>(
        p_bf, vt_bf, out_ws, nullptr, 2048, 1024, 2048,
        (long)S * S, (long)S * H, (long)S * H, 1.f);
}

// Round 2
// 318.051 us; speedup vs baseline: 1.1369x; 1.1369x over previous
//
#include <hip/hip_runtime.h>
#include <hip/hip_bf16.h>
#include <cstdint>

// ---------------------------------------------------------------------------
// SelfAttention: q,k,v = x@W{q,k,v}^T + b ; P = softmax(qk^T/sqrt(H)) ; out = P@v
// B=4, S=2048, H=I=1024. fp32 I/O, bf16 MFMA internally (tol 6.25e-3).
// R2: BK=64 (32 MFMA/barrier), XOR-swizzled LDS (bank-conflict-free frag reads),
//     fused QKV GEMM (N=3072).
// ---------------------------------------------------------------------------

typedef __bf16 bf16x8 __attribute__((ext_vector_type(8)));
typedef float  f32x4  __attribute__((ext_vector_type(4)));

__device__ __forceinline__ void load_lds16(const __bf16* g, __bf16* l) {
    __builtin_amdgcn_global_load_lds(
        (const __attribute__((address_space(1))) void*)g,
        (__attribute__((address_space(3))) void*)l,
        16, 0, 0);
}

// ---------------- fp32 -> bf16 convert (8 elems / thread) ------------------
__global__ __launch_bounds__(256) void cvt_f32_bf16(
        const float* __restrict__ src, __bf16* __restrict__ dst, int n8) {
    int i = blockIdx.x * blockDim.x + threadIdx.x;
    if (i >= n8) return;
    const float4* s4 = (const float4*)src;
    float4 a = s4[2 * i], b = s4[2 * i + 1];
    bf16x8 o;
    o[0] = (__bf16)a.x; o[1] = (__bf16)a.y; o[2] = (__bf16)a.z; o[3] = (__bf16)a.w;
    o[4] = (__bf16)b.x; o[5] = (__bf16)b.y; o[6] = (__bf16)b.z; o[7] = (__bf16)b.w;
    ((bf16x8*)dst)[i] = o;
}

// ---------------- pack 3x1024 biases into one 3072 buffer ------------------
__global__ __launch_bounds__(256) void pack_bias3(
        const float* __restrict__ a, const float* __restrict__ b,
        const float* __restrict__ c, float* __restrict__ o) {
    int i = blockIdx.x * blockDim.x + threadIdx.x;
    if (i < 1024) { o[i] = a[i]; o[i + 1024] = b[i]; o[i + 2048] = c[i]; }
}

// ---------------- NT bf16 GEMM: C[m,n] = sum_k A[m,k] * Bt[n,k] ------------
// 128x128 tile, BK=64, 4 waves (2x2 of 64x64), 16x16x32 MFMA, 4x4 frags/wave.
// LDS layout: 16B chunks, chunk (row, cs) holds global chunk cg = cs ^ (row&7).
// MODE 0: bf16 = acc + bias[n], scattered to C0/C1/C2 by n>>10 (fused QKV)
// MODE 1: f32  = acc * scale   (scores)
// MODE 2: f32  = acc           (PV)
template <int MODE>
__global__ __launch_bounds__(256, 3) void gemm_nt(
        const __bf16* __restrict__ A, const __bf16* __restrict__ Bt,
        void* __restrict__ C0, void* __restrict__ C1, void* __restrict__ C2,
        const float* __restrict__ bias,
        int lda, int ldb, int ldc, long sA, long sB, long sC,
        int K, float scale) {
    __shared__ __bf16 lA[128 * 64];
    __shared__ __bf16 lB[128 * 64];

    const int tid  = threadIdx.x;
    const int lane = tid & 63;
    const int wave = tid >> 6;
    const int mblk = blockIdx.y * 128;
    const int nblk = blockIdx.x * 128;
    const int z    = blockIdx.z;
    A  += (long)z * sA;
    Bt += (long)z * sB;

    const int wm = (wave >> 1) * 64;   // wave m offset in tile
    const int wn = (wave & 1) * 64;    // wave n offset in tile

    f32x4 zero = {0.f, 0.f, 0.f, 0.f};
    f32x4 acc[4][4];
#pragma unroll
    for (int i = 0; i < 4; ++i)
#pragma unroll
        for (int j = 0; j < 4; ++j) acc[i][j] = zero;

    const int rsel = lane & 15;        // row-in-16 selector for A/B frags
    const int quad = lane >> 4;        // k-chunk selector (0..3)

    // staging addresses (swizzled source chunk per lane)
    int srow[4], scol[4];
#pragma unroll
    for (int it = 0; it < 4; ++it) {
        int s  = tid + it * 256;       // LDS slot 0..1023 (lane-ordered)
        srow[it] = s >> 3;
        scol[it] = ((s & 7) ^ (srow[it] & 7)) * 8;  // swizzled global col
    }

    for (int k0 = 0; k0 < K; k0 += 64) {
#pragma unroll
        for (int it = 0; it < 4; ++it) {
            int s = tid + it * 256;
            load_lds16(A  + (long)(mblk + srow[it]) * lda + k0 + scol[it], lA + s * 8);
            load_lds16(Bt + (long)(nblk + srow[it]) * ldb + k0 + scol[it], lB + s * 8);
        }
        __syncthreads();

#pragma unroll
        for (int half = 0; half < 2; ++half) {
            const int cq = quad + half * 4;   // needed global chunk col
            bf16x8 fa[4], fb[4];
#pragma unroll
            for (int i = 0; i < 4; ++i) {
                int ra = wm + i * 16 + rsel;
                fa[i] = *(const bf16x8*)&lA[(ra * 8 + (cq ^ (ra & 7))) * 8];
                int rb = wn + i * 16 + rsel;
                fb[i] = *(const bf16x8*)&lB[(rb * 8 + (cq ^ (rb & 7))) * 8];
            }
#pragma unroll
            for (int i = 0; i < 4; ++i)
#pragma unroll
                for (int j = 0; j < 4; ++j)
                    acc[i][j] = __builtin_amdgcn_mfma_f32_16x16x32_bf16(
                        fa[i], fb[j], acc[i][j], 0, 0, 0);
        }
        __syncthreads();
    }

    // epilogue: lane holds C[m = wm+i*16+(lane>>4)*4+r][n = wn+j*16+rsel]
    const int rq = quad * 4;
#pragma unroll
    for (int i = 0; i < 4; ++i) {
#pragma unroll
        for (int j = 0; j < 4; ++j) {
            const int n = nblk + wn + j * 16 + rsel;
            if constexpr (MODE == 0) {
                __bf16* C = (n < 1024) ? (__bf16*)C0
                          : (n < 2048) ? (__bf16*)C1 : (__bf16*)C2;
                const int col = n & 1023;
                float bv = bias[n];
#pragma unroll
                for (int r = 0; r < 4; ++r) {
                    int m = mblk + wm + i * 16 + rq + r;
                    C[(long)m * ldc + col] = (__bf16)(acc[i][j][r] + bv);
                }
            } else if constexpr (MODE == 1) {
                float* C = (float*)C0 + (long)z * sC;
#pragma unroll
                for (int r = 0; r < 4; ++r) {
                    int m = mblk + wm + i * 16 + rq + r;
                    C[(long)m * ldc + n] = acc[i][j][r] * scale;
                }
            } else {
                float* C = (float*)C0 + (long)z * sC;
#pragma unroll
                for (int r = 0; r < 4; ++r) {
                    int m = mblk + wm + i * 16 + rq + r;
                    C[(long)m * ldc + n] = acc[i][j][r];
                }
            }
        }
    }
}

// ---------------- row softmax over 2048 floats, in-place + bf16 copy -------
__global__ __launch_bounds__(256) void softmax_rows(
        float* __restrict__ P, __bf16* __restrict__ Pb) {
    const long row = blockIdx.x;           // 8192 rows
    float*  p  = P  + row * 2048;
    __bf16* pb = Pb + row * 2048;
    const int tid  = threadIdx.x;
    const int lane = tid & 63;
    const int wave = tid >> 6;

    float4 v0 = ((const float4*)p)[tid * 2];
    float4 v1 = ((const float4*)p)[tid * 2 + 1];
    float e[8] = {v0.x, v0.y, v0.z, v0.w, v1.x, v1.y, v1.z, v1.w};

    float mx = e[0];
#pragma unroll
    for (int i = 1; i < 8; ++i) mx = fmaxf(mx, e[i]);
#pragma unroll
    for (int o = 1; o < 64; o <<= 1) mx = fmaxf(mx, __shfl_xor(mx, o, 64));

    __shared__ float redm[4], reds[4];
    if (lane == 0) redm[wave] = mx;
    __syncthreads();
    mx = fmaxf(fmaxf(redm[0], redm[1]), fmaxf(redm[2], redm[3]));

    float sum = 0.f;
#pragma unroll
    for (int i = 0; i < 8; ++i) { e[i] = __expf(e[i] - mx); sum += e[i]; }
#pragma unroll
    for (int o = 1; o < 64; o <<= 1) sum += __shfl_xor(sum, o, 64);
    if (lane == 0) reds[wave] = sum;
    __syncthreads();
    sum = reds[0] + reds[1] + reds[2] + reds[3];
    const float inv = 1.f / sum;

    float4 o0, o1;
    o0.x = e[0] * inv; o0.y = e[1] * inv; o0.z = e[2] * inv; o0.w = e[3] * inv;
    o1.x = e[4] * inv; o1.y = e[5] * inv; o1.z = e[6] * inv; o1.w = e[7] * inv;
    ((float4*)p)[tid * 2]     = o0;
    ((float4*)p)[tid * 2 + 1] = o1;
    bf16x8 ob;
    ob[0] = (__bf16)o0.x; ob[1] = (__bf16)o0.y; ob[2] = (__bf16)o0.z; ob[3] = (__bf16)o0.w;
    ob[4] = (__bf16)o1.x; ob[5] = (__bf16)o1.y; ob[6] = (__bf16)o1.z; ob[7] = (__bf16)o1.w;
    ((bf16x8*)pb)[tid] = ob;
}

// ---------------- bf16 transpose: V[b][t][h] -> Vt[b][h][t] ----------------
__global__ __launch_bounds__(256) void transpose_v(
        const __bf16* __restrict__ src, __bf16* __restrict__ dst) {
    __shared__ __bf16 t[32][33];
    const int tx = threadIdx.x, ty = threadIdx.y;   // (32, 8)
    const int tileC = blockIdx.x * 32;              // h base (0..1023)
    const int tileR = blockIdx.y * 32;              // t base (0..2047)
    const long zs = (long)blockIdx.z * 2048 * 1024;
    const long zd = (long)blockIdx.z * 1024 * 2048;
#pragma unroll
    for (int k = 0; k < 4; ++k) {
        int r = ty * 4 + k;
        t[r][tx] = src[zs + (long)(tileR + r) * 1024 + tileC + tx];
    }
    __syncthreads();
#pragma unroll
    for (int k = 0; k < 4; ++k) {
        int c = ty * 4 + k;
        dst[zd + (long)(tileC + c) * 2048 + tileR + tx] = t[tx][c];
    }
}

// ---------------------------------------------------------------------------
extern "C" void kernel_launch(void* const* d_in, const int* in_sizes, int n_in,
                              void* d_out, int out_size, void* d_ws, size_t ws_size,
                              hipStream_t stream) {
    const float* x  = (const float*)d_in[0];
    const float* Wq = (const float*)d_in[1];
    const float* bq = (const float*)d_in[2];
    const float* Wk = (const float*)d_in[3];
    const float* bk = (const float*)d_in[4];
    const float* Wv = (const float*)d_in[5];
    const float* bv = (const float*)d_in[6];

    const int  S = 2048, H = 1024, I = 1024, B = 4;
    const long MS = (long)B * S;              // 8192 rows
    float* out_ws  = (float*)d_out;                     // [B][S][H]
    float* out_att = (float*)d_out + (long)B * S * H;   // [B][S][S]

    char* w = (char*)d_ws;
    __bf16* x_bf   = (__bf16*)w; w += MS * I * 2;           // 16 MB
    __bf16* wqkv   = (__bf16*)w; w += (long)3 * H * I * 2;  //  6 MB
    float*  bias3  = (float*)w;  w += 4096 * 4;             // 16 KB
    __bf16* q_bf   = (__bf16*)w; w += MS * H * 2;           // 16 MB
    __bf16* k_bf   = (__bf16*)w; w += MS * H * 2;
    __bf16* v_bf   = (__bf16*)w; w += MS * H * 2;
    __bf16* vt_bf  = (__bf16*)w; w += MS * H * 2;
    __bf16* p_bf   = (__bf16*)w; w += (long)B * S * S * 2;  // 32 MB

    // 1) converts + bias pack
    {
        int n8 = (int)(MS * I / 8);
        cvt_f32_bf16<<<dim3((n8 + 255) / 256), dim3(256), 0, stream>>>(x, x_bf, n8);
        int w8 = H * I / 8;
        cvt_f32_bf16<<<dim3((w8 + 255) / 256), dim3(256), 0, stream>>>(Wq, wqkv, w8);
        cvt_f32_bf16<<<dim3((w8 + 255) / 256), dim3(256), 0, stream>>>(Wk, wqkv + (long)H * I, w8);
        cvt_f32_bf16<<<dim3((w8 + 255) / 256), dim3(256), 0, stream>>>(Wv, wqkv + (long)2 * H * I, w8);
        pack_bias3<<<dim3(4), dim3(256), 0, stream>>>(bq, bk, bv, bias3);
    }

    // 2) fused QKV projection: M=8192, N=3072, K=1024
    gemm_nt<0><<<dim3(24, 64, 1), dim3(256), 0, stream>>>(
        x_bf, wqkv, q_bf, k_bf, v_bf, bias3,
        1024, 1024, 1024, 0, 0, 0, 1024, 1.f);

    // 3) V transpose for PV GEMM
    transpose_v<<<dim3(32, 64, 4), dim3(32, 8), 0, stream>>>(v_bf, vt_bf);

    // 4) scores = Q K^T * 1/32 -> fp32 into attn-weights output region
    gemm_nt<1><<<dim3(16, 16, 4), dim3(256), 0, stream>>>(
        q_bf, k_bf, out_att, nullptr, nullptr, nullptr,
        1024, 1024, 2048, (long)S * H, (long)S * H, (long)S * S, 1024, 0.03125f);

    // 5) softmax rows in-place (+ bf16 copy for PV)
    softmax_rows<<<dim3(8192), dim3(256), 0, stream>>>(out_att, p_bf);

    // 6) weighted_sum = P V : M=2048, N=1024, K=2048 per batch
    gemm_nt<2><<<dim3(8, 16, 4), dim3(256), 0, stream>>>(
        p_bf, vt_bf, out_ws, nullptr, nullptr, nullptr,
        2048, 2048, 1024, (long)S * S, (long)S * H, (long)S * H, 2048, 1.f);
}